// Round 8
// baseline (165.636 us; speedup 1.0000x reference)
//
#include <hip/hip_runtime.h>

typedef unsigned short u16;
typedef unsigned int u32;
typedef __attribute__((ext_vector_type(8))) short short8;
typedef __attribute__((ext_vector_type(4))) float f32x4;

__device__ __forceinline__ u16 f2b(float f) {
  union { float f; u32 i; } v; v.f = f;
  u32 i = v.i;
  return (u16)((i + 0x7FFFu + ((i >> 16) & 1u)) >> 16);
}
__device__ __forceinline__ float lo16(u32 x) { union { u32 i; float f; } v; v.i = x << 16; return v.f; }
__device__ __forceinline__ float hi16(u32 x) { union { u32 i; float f; } v; v.i = x & 0xffff0000u; return v.f; }
__device__ __forceinline__ u32 pack2(float a, float b) { return (u32)f2b(a) | ((u32)f2b(b) << 16); }

// Sizes: N=2, M=512, D_IN=64, D=128, H=8. Rows = N*M = 1024. hn = h*2+n in [0,16).
__device__ __align__(16) float g_h[1024 * 128];
__device__ __align__(16) u16   g_hb[1024 * 128];
__device__ __align__(16) u16   g_Wt[24 * 128 * 128];   // W^T per (proj,head): [ph][e][d] bf16
__device__ __align__(16) u16   g_w1t[128 * 1024];      // fv_w1^T: [e][k] bf16
__device__ __align__(16) u16   g_K[16 * 512 * 128];
__device__ __align__(16) u16   g_Q[16 * 512 * 128];
__device__ __align__(16) u16   g_V[16 * 512 * 128];
__device__ __align__(16) u16   g_Opb[512 * 64 * 128];  // bf16 flash partials
__device__ __align__(16) float g_ml[512 * 64 * 2];
__device__ __align__(16) float g_part8[8 * 1024 * 128];
__device__ __align__(16) float g_A[1024 * 128];
__device__ __align__(16) float g_Bm[1024 * 128];

// ---------------- Kernel 1: f_node, SHALLOW-WIDE (1024 blocks, 1 row each) ------
// Per-thread-output formulation: thread j owns hid[j] (64 serial FMAs, LDS-
// broadcast xr, coalesced w1 column reads); then thread (e,half) owns half of
// x2[e]. 2 sync-separated stages instead of 9; 4 blocks/CU instead of 2.
__global__ __launch_bounds__(256) void k_fnode(
    const float* __restrict__ x, const float* __restrict__ w1,
    const float* __restrict__ b1, const float* __restrict__ w2,
    const float* __restrict__ b2, const float* __restrict__ wk,
    const float* __restrict__ wq, const float* __restrict__ wv,
    const float* __restrict__ fvw1) {
  __shared__ float xr[64];
  __shared__ float hids[256];
  __shared__ float red[256];
  int tx = threadIdx.x, b = blockIdx.x;
  if (tx < 64) xr[tx] = x[b * 64 + tx] + sinf((float)tx * (5.0f / 63.0f));
  // piggyback: transpose weights to bf16 (524288 items over 1024 blocks x 2)
#pragma unroll
  for (int t = 0; t < 2; t++) {
    int idx = t * 262144 + b * 256 + tx;
    if (idx < 393216) {
      int ph = idx >> 14, rem = idx & 16383, e = rem >> 7, d = rem & 127;
      int proj = ph >> 3, head = ph & 7;
      const float* W = (proj == 0) ? wk : (proj == 1) ? wq : wv;
      g_Wt[idx] = f2b(W[head * 16384 + d * 128 + e]);
    } else {
      int idx2 = idx - 393216;          // fv_w1^T
      int e = idx2 >> 10, k = idx2 & 1023;
      g_w1t[idx2] = f2b(fvw1[k * 128 + e]);
    }
  }
  __syncthreads();
  // stage 1: hid[tx] = relu(x @ w1 + b1)   (64 FMAs, no reduction)
  {
    float acc = 0.0f;
#pragma unroll 16
    for (int k = 0; k < 64; k++) acc = fmaf(xr[k], w1[k * 256 + tx], acc);
    hids[tx] = fmaxf(acc + b1[tx], 0.0f);
  }
  __syncthreads();
  // stage 2: x2[e] = hid @ w2 + b2  (k split in 2 halves, one LDS pair-reduce)
  {
    int e = tx & 127, half = tx >> 7;
    float acc = 0.0f;
#pragma unroll 16
    for (int i = 0; i < 128; i++) {
      int k = half * 128 + i;
      acc = fmaf(hids[k], w2[k * 128 + e], acc);
    }
    red[tx] = acc;
  }
  __syncthreads();
  if (tx < 128) {
    float v = red[tx] + red[128 + tx] + b2[tx];
    g_h[b * 128 + tx] = v;
    g_hb[b * 128 + tx] = f2b(v);
  }
}

// ---------------- Kernel 2: K/Q/V projections via MFMA (pre-transposed W) --------
__global__ __launch_bounds__(256) void k_kqv(
    const float* __restrict__ bk, const float* __restrict__ bq,
    const float* __restrict__ bv) {
  __shared__ u16 hs[64 * 136];
  __shared__ u16 Wt[128 * 136];
  int b = blockIdx.x, tx = threadIdx.x;
  int rt = b & 15, ph = b >> 4;
  int proj = ph >> 3, head = ph & 7;
  const float* Bb = (proj == 0) ? bk : (proj == 1) ? bq : bv;
  u16* O = (proj == 0) ? g_K : (proj == 1) ? g_Q : g_V;
  int r0 = rt * 64;
#pragma unroll
  for (int t = 0; t < 4; t++) {
    int idx = t * 256 + tx, row = idx >> 4, oct = idx & 15;
    *(uint4*)&hs[row * 136 + oct * 8] = *(const uint4*)&g_hb[(r0 + row) * 128 + oct * 8];
  }
  const u16* Wtg = g_Wt + ph * 16384;
#pragma unroll
  for (int t = 0; t < 8; t++) {
    int idx = t * 256 + tx, row = idx >> 4, oct = idx & 15;
    *(uint4*)&Wt[row * 136 + oct * 8] = *(const uint4*)&Wtg[row * 128 + oct * 8];
  }
  __syncthreads();
  int lane = tx & 63, wv_ = tx >> 6, cl = lane & 15, quad = lane >> 4;
  short8 bH[4];
#pragma unroll
  for (int kk = 0; kk < 4; kk++)
    bH[kk] = *(const short8*)&hs[(wv_ * 16 + cl) * 136 + kk * 32 + quad * 8];
  f32x4 zero = {0.0f, 0.0f, 0.0f, 0.0f};
  f32x4 acc[8];
#pragma unroll
  for (int em = 0; em < 8; em++) acc[em] = zero;
#pragma unroll
  for (int em = 0; em < 8; em++)
#pragma unroll
    for (int kk = 0; kk < 4; kk++) {
      short8 aW = *(const short8*)&Wt[(em * 16 + cl) * 136 + kk * 32 + quad * 8];
      acc[em] = __builtin_amdgcn_mfma_f32_16x16x32_bf16(aW, bH[kk], acc[em], 0, 0, 0);
    }
#pragma unroll
  for (int em = 0; em < 8; em++) {
    float4 b4 = *(const float4*)&Bb[head * 128 + em * 16 + quad * 4];
    uint2 st = make_uint2(pack2(acc[em][0] + b4.x, acc[em][1] + b4.y),
                          pack2(acc[em][2] + b4.z, acc[em][3] + b4.w));
    *(uint2*)&O[(head * 1024 + r0 + wv_ * 16 + cl) * 128 + em * 16 + quad * 4] = st;
  }
}

// ---------------- Kernel 3: attention via MFMA, bf16 partials out ----------------
__global__ __launch_bounds__(256) void k_attn() {
  __shared__ u16 Ks[64 * 136];
  __shared__ u16 Qs[64 * 136];
  __shared__ u16 Vt[128 * 72];
  __shared__ u16 Pw[4 * 16 * 72];
  __shared__ float alphas[4 * 16];
  int b = blockIdx.x, tx = threadIdx.x;
  int jc = b & 3, it = (b >> 2) & 7, hn = b >> 5;
  int i0 = it * 64;
  const u16* Kp = g_K + hn * 65536;
  const u16* Qp = g_Q + hn * 65536;
  const u16* Vp = g_V + hn * 65536;
#pragma unroll
  for (int t = 0; t < 4; t++) {
    int idx = t * 256 + tx, row = idx >> 4, oct = idx & 15;
    *(uint4*)&Ks[row * 136 + oct * 8] = *(const uint4*)&Kp[(i0 + row) * 128 + oct * 8];
  }
  int lane = tx & 63, wv = tx >> 6;
  int cl = lane & 15, quad = lane >> 4;
  f32x4 zero = {0.0f, 0.0f, 0.0f, 0.0f};
  f32x4 o[8];
#pragma unroll
  for (int es = 0; es < 8; es++) o[es] = zero;
  float m_ = -1e30f, l_ = 0.0f;

  for (int jt = 0; jt < 2; jt++) {
    int j0 = jc * 128 + jt * 64;
    __syncthreads();
#pragma unroll
    for (int t = 0; t < 4; t++) {
      int idx = t * 256 + tx, row = idx >> 4, oct = idx & 15;
      *(uint4*)&Qs[row * 136 + oct * 8] = *(const uint4*)&Qp[(j0 + row) * 128 + oct * 8];
    }
    {
      int jg = (tx & 15) * 4, e8 = (tx >> 4) * 8;
      uint4 r0 = *(const uint4*)&Vp[(j0 + jg + 0) * 128 + e8];
      uint4 r1 = *(const uint4*)&Vp[(j0 + jg + 1) * 128 + e8];
      uint4 r2 = *(const uint4*)&Vp[(j0 + jg + 2) * 128 + e8];
      uint4 r3 = *(const uint4*)&Vp[(j0 + jg + 3) * 128 + e8];
      const u32* p0 = (const u32*)&r0; const u32* p1 = (const u32*)&r1;
      const u32* p2 = (const u32*)&r2; const u32* p3 = (const u32*)&r3;
#pragma unroll
      for (int c = 0; c < 8; c++) {
        int w = c >> 1, sh = (c & 1) * 16;
        u32 lo = ((p0[w] >> sh) & 0xffffu) | (((p1[w] >> sh) & 0xffffu) << 16);
        u32 hi = ((p2[w] >> sh) & 0xffffu) | (((p3[w] >> sh) & 0xffffu) << 16);
        *(uint2*)&Vt[(e8 + c) * 72 + jg] = make_uint2(lo, hi);
      }
    }
    __syncthreads();
    short8 bK[4];
#pragma unroll
    for (int kk = 0; kk < 4; kk++)
      bK[kk] = *(const short8*)&Ks[(wv * 16 + cl) * 136 + kk * 32 + quad * 8];
    f32x4 st[4];
#pragma unroll
    for (int s = 0; s < 4; s++) {
      f32x4 acc = zero;
#pragma unroll
      for (int kk = 0; kk < 4; kk++) {
        short8 aQ = *(const short8*)&Qs[(s * 16 + cl) * 136 + kk * 32 + quad * 8];
        acc = __builtin_amdgcn_mfma_f32_16x16x32_bf16(aQ, bK[kk], acc, 0, 0, 0);
      }
      st[s] = acc;
    }
    float p[4][4];
    float tm = -1e30f;
#pragma unroll
    for (int s = 0; s < 4; s++)
#pragma unroll
      for (int r = 0; r < 4; r++) {
        float v = st[s][r];
        v = fmaxf(v, 0.2f * v);
        p[s][r] = v;
        tm = fmaxf(tm, v);
      }
    tm = fmaxf(tm, __shfl_xor(tm, 16));
    tm = fmaxf(tm, __shfl_xor(tm, 32));
    float mn = fmaxf(m_, tm);
    float alpha = __expf(m_ - mn);
    m_ = mn;
    float ps = 0.0f;
#pragma unroll
    for (int s = 0; s < 4; s++)
#pragma unroll
      for (int r = 0; r < 4; r++) {
        float e = __expf(p[s][r] - mn);
        p[s][r] = e;
        ps += e;
      }
    ps += __shfl_xor(ps, 16);
    ps += __shfl_xor(ps, 32);
    l_ = l_ * alpha + ps;
#pragma unroll
    for (int s = 0; s < 4; s++) {
      uint2 w2v = make_uint2(pack2(p[s][0], p[s][1]), pack2(p[s][2], p[s][3]));
      *(uint2*)&Pw[(wv * 16 + cl) * 72 + s * 16 + quad * 4] = w2v;
    }
    if (quad == 0) alphas[wv * 16 + cl] = alpha;
    __syncthreads();
    f32x4 av = *(const f32x4*)&alphas[wv * 16 + quad * 4];
#pragma unroll
    for (int es = 0; es < 8; es++) o[es] *= av;
    short8 aP[2];
#pragma unroll
    for (int k2 = 0; k2 < 2; k2++)
      aP[k2] = *(const short8*)&Pw[(wv * 16 + cl) * 72 + k2 * 32 + quad * 8];
#pragma unroll
    for (int es = 0; es < 8; es++) {
#pragma unroll
      for (int k2 = 0; k2 < 2; k2++) {
        short8 bV = *(const short8*)&Vt[(es * 16 + cl) * 72 + k2 * 32 + quad * 8];
        o[es] = __builtin_amdgcn_mfma_f32_16x16x32_bf16(aP[k2], bV, o[es], 0, 0, 0);
      }
    }
  }
#pragma unroll
  for (int es = 0; es < 8; es++)
#pragma unroll
    for (int r = 0; r < 4; r++)
      g_Opb[(b * 64 + wv * 16 + quad * 4 + r) * 128 + es * 16 + cl] = f2b(o[es][r]);
  if (quad == 0) {
    g_ml[(b * 64 + wv * 16 + cl) * 2 + 0] = m_;
    g_ml[(b * 64 + wv * 16 + cl) * 2 + 1] = l_;
  }
}

// ---------------- Kernel 4a: fused merge + att@fv_w1 via MFMA --------------------
__global__ __launch_bounds__(256) void k_fv1() {
  __shared__ u16 atts[64 * 136];
  __shared__ u16 w1t[128 * 136];
  int b = blockIdx.x, tx = threadIdx.x;
  int kc = b & 7, rt = b >> 3;
  int r0 = rt * 64, k0 = kc * 128;
  int hn = kc * 2 + (rt >> 3), it = rt & 7;
#pragma unroll
  for (int t = 0; t < 8; t++) {
    int idx = t * 256 + tx, row = idx >> 4, oct = idx & 15;
    *(uint4*)&w1t[row * 136 + oct * 8] = *(const uint4*)&g_w1t[row * 1024 + k0 + oct * 8];
  }
  {
    int row = tx >> 2, cs = (tx & 3) * 32;
    float mc[4], lc[4];
#pragma unroll
    for (int c = 0; c < 4; c++) {
      float2 ml = *(const float2*)&g_ml[((hn * 32 + it * 4 + c) * 64 + row) * 2];
      mc[c] = ml.x; lc[c] = ml.y;
    }
    float ms = fmaxf(fmaxf(mc[0], mc[1]), fmaxf(mc[2], mc[3]));
    float lsum = 0.0f;
    float ra[32];
#pragma unroll
    for (int i = 0; i < 32; i++) ra[i] = 0.0f;
#pragma unroll
    for (int c = 0; c < 4; c++) {
      float w = __expf(mc[c] - ms);
      lsum += w * lc[c];
      const u16* src = &g_Opb[((hn * 32 + it * 4 + c) * 64 + row) * 128 + cs];
#pragma unroll
      for (int ov = 0; ov < 4; ov++) {
        uint4 v = *(const uint4*)&src[ov * 8];
        ra[ov * 8 + 0] = fmaf(w, lo16(v.x), ra[ov * 8 + 0]);
        ra[ov * 8 + 1] = fmaf(w, hi16(v.x), ra[ov * 8 + 1]);
        ra[ov * 8 + 2] = fmaf(w, lo16(v.y), ra[ov * 8 + 2]);
        ra[ov * 8 + 3] = fmaf(w, hi16(v.y), ra[ov * 8 + 3]);
        ra[ov * 8 + 4] = fmaf(w, lo16(v.z), ra[ov * 8 + 4]);
        ra[ov * 8 + 5] = fmaf(w, hi16(v.z), ra[ov * 8 + 5]);
        ra[ov * 8 + 6] = fmaf(w, lo16(v.w), ra[ov * 8 + 6]);
        ra[ov * 8 + 7] = fmaf(w, hi16(v.w), ra[ov * 8 + 7]);
      }
    }
    float inv = 1.0f / lsum;
    u32 pk[16];
#pragma unroll
    for (int i = 0; i < 16; i++) {
      float v0 = ra[i * 2] * inv;     v0 = fmaxf(v0, 0.2f * v0);
      float v1 = ra[i * 2 + 1] * inv; v1 = fmaxf(v1, 0.2f * v1);
      pk[i] = pack2(v0, v1);
    }
#pragma unroll
    for (int ov = 0; ov < 4; ov++)
      *(uint4*)&atts[row * 136 + cs + ov * 8] =
          make_uint4(pk[ov * 4], pk[ov * 4 + 1], pk[ov * 4 + 2], pk[ov * 4 + 3]);
  }
  __syncthreads();
  int lane = tx & 63, wv_ = tx >> 6, cl = lane & 15, quad = lane >> 4;
  short8 bA[4];
#pragma unroll
  for (int kk = 0; kk < 4; kk++)
    bA[kk] = *(const short8*)&atts[(wv_ * 16 + cl) * 136 + kk * 32 + quad * 8];
  f32x4 zero = {0.0f, 0.0f, 0.0f, 0.0f};
  f32x4 acc[8];
#pragma unroll
  for (int em = 0; em < 8; em++) acc[em] = zero;
#pragma unroll
  for (int em = 0; em < 8; em++)
#pragma unroll
    for (int kk = 0; kk < 4; kk++) {
      short8 aW = *(const short8*)&w1t[(em * 16 + cl) * 136 + kk * 32 + quad * 8];
      acc[em] = __builtin_amdgcn_mfma_f32_16x16x32_bf16(aW, bA[kk], acc[em], 0, 0, 0);
    }
#pragma unroll
  for (int em = 0; em < 8; em++)
    *(f32x4*)&g_part8[kc * 131072 + (r0 + wv_ * 16 + cl) * 128 + em * 16 + quad * 4] =
        acc[em];
}

// ---------------- Kernel 4b: SHALLOW-WIDE fv2 (1024 blocks, 1 row each) ---------
// Per-thread-output: thread (e,half) owns half of each K=128 dot product; one
// LDS pair-reduce per gemm. 6 syncs instead of 8 red-stage round-trips.
__global__ __launch_bounds__(256) void k_fv2(
    const float* __restrict__ b1, const float* __restrict__ w2,
    const float* __restrict__ b2, const float* __restrict__ few1,
    const float* __restrict__ feb1, float* __restrict__ x2out) {
  __shared__ float hid[128];
  __shared__ float x2s[128];
  __shared__ float red[256];
  int b = blockIdx.x, tx = threadIdx.x;
  int e = tx & 127, half = tx >> 7;
  // stage A: hid = relu(sum of 8 partials + b1)
  if (tx < 128) {
    float s = b1[tx];
#pragma unroll
    for (int kc = 0; kc < 8; kc++) s += g_part8[kc * 131072 + b * 128 + tx];
    hid[tx] = fmaxf(s, 0.0f);
  }
  __syncthreads();
  // stage B: x2 = hid @ fv_w2 + b2 + h (residual)
  {
    float acc = 0.0f;
#pragma unroll 16
    for (int i = 0; i < 64; i++) {
      int k = half * 64 + i;
      acc = fmaf(hid[k], w2[k * 128 + e], acc);
    }
    red[tx] = acc;
  }
  __syncthreads();
  if (tx < 128) {
    float c = red[tx] + red[128 + tx] + b2[tx] + g_h[b * 128 + tx];
    x2s[tx] = c;
    x2out[b * 128 + tx] = c;
  }
  __syncthreads();
  // stage C: A = x2 @ feA + feb1 ; B = x2 @ feB
  float aA = 0.0f, aB = 0.0f;
#pragma unroll 16
  for (int i = 0; i < 64; i++) {
    int k = half * 64 + i;
    float xv = x2s[k];
    aA = fmaf(xv, few1[k * 128 + e], aA);
    aB = fmaf(xv, few1[(128 + k) * 128 + e], aB);
  }
  red[tx] = aA;
  __syncthreads();
  if (tx < 128) g_A[b * 128 + tx] = red[tx] + red[128 + tx] + feb1[tx];
  __syncthreads();
  red[tx] = aB;
  __syncthreads();
  if (tx < 128) g_Bm[b * 128 + tx] = red[tx] + red[128 + tx];
}

// ---------------- Kernel 5: pairwise edge FFN (A_i + B_j factorized) -------------
__global__ void k_edge(const float* __restrict__ few2, const float* __restrict__ feb2,
                       float* __restrict__ edge) {
  __shared__ float As[4 * 128];
  __shared__ float w2s[128];
  int b = blockIdx.x, tx = threadIdx.x;
  int n = b >> 8, rest = b & 255, ig = rest >> 1, jh = rest & 1;
  int i0 = ig * 4;
  if (tx < 128) w2s[tx] = few2[tx];
  As[tx] = g_A[(n * 512 + i0) * 128 + tx];
  As[tx + 256] = g_A[(n * 512 + i0) * 128 + tx + 256];
  float eb2 = feb2[0];
  __syncthreads();
  int j = jh * 256 + tx;
  const float* B0 = &g_Bm[(n * 512 + j) * 128];
  float acc[4] = {};
#pragma unroll 4
  for (int dc = 0; dc < 32; dc++) {
    float4 bv = *(const float4*)&B0[dc * 4];
    float4 w4 = *(const float4*)&w2s[dc * 4];
#pragma unroll
    for (int i = 0; i < 4; i++) {
      float4 a4 = *(const float4*)&As[i * 128 + dc * 4];
      acc[i] = fmaf(fmaxf(a4.x + bv.x, 0.0f), w4.x, acc[i]);
      acc[i] = fmaf(fmaxf(a4.y + bv.y, 0.0f), w4.y, acc[i]);
      acc[i] = fmaf(fmaxf(a4.z + bv.z, 0.0f), w4.z, acc[i]);
      acc[i] = fmaf(fmaxf(a4.w + bv.w, 0.0f), w4.w, acc[i]);
    }
  }
  const float scale = 1.0f / 512.0f;
#pragma unroll
  for (int i = 0; i < 4; i++)
    edge[(n * 512 + i0 + i) * 512 + j] = (acc[i] + eb2) * scale;
}

extern "C" void kernel_launch(void* const* d_in, const int* in_sizes, int n_in,
                              void* d_out, int out_size, void* d_ws, size_t ws_size,
                              hipStream_t stream) {
  (void)in_sizes; (void)n_in; (void)out_size; (void)d_ws; (void)ws_size;
  const float* x     = (const float*)d_in[0];
  const float* fn_w1 = (const float*)d_in[1];
  const float* fn_b1 = (const float*)d_in[2];
  const float* fn_w2 = (const float*)d_in[3];
  const float* fn_b2 = (const float*)d_in[4];
  const float* wk    = (const float*)d_in[5];
  const float* bk    = (const float*)d_in[6];
  const float* wq    = (const float*)d_in[7];
  const float* bq    = (const float*)d_in[8];
  const float* wv    = (const float*)d_in[9];
  const float* bv    = (const float*)d_in[10];
  const float* fv_w1 = (const float*)d_in[11];
  const float* fv_b1 = (const float*)d_in[12];
  const float* fv_w2 = (const float*)d_in[13];
  const float* fv_b2 = (const float*)d_in[14];
  const float* fe_w1 = (const float*)d_in[15];
  const float* fe_b1 = (const float*)d_in[16];
  const float* fe_w2 = (const float*)d_in[17];
  const float* fe_b2 = (const float*)d_in[18];

  float* x2out = (float*)d_out;      // [0, 131072) floats
  float* edge  = x2out + 131072;     // [131072, 655360) floats

  k_fnode<<<1024, 256, 0, stream>>>(x, fn_w1, fn_b1, fn_w2, fn_b2, wk, wq, wv, fv_w1);
  k_kqv<<<384, 256, 0, stream>>>(bk, bq, bv);
  k_attn<<<512, 256, 0, stream>>>();
  k_fv1<<<128, 256, 0, stream>>>();
  k_fv2<<<1024, 256, 0, stream>>>(fv_b1, fv_w2, fv_b2, fe_w1, fe_b1, x2out);
  k_edge<<<512, 256, 0, stream>>>(fe_w2, fe_b2, edge);
}